// Round 2
// baseline (471.283 us; speedup 1.0000x reference)
//
#include <hip/hip_runtime.h>
#include <stdint.h>

// Problem constants
#define DD  128     // latent dim
#define HH  132     // FCBlock hidden width
#define BB  65536   // batch
#define KKC 8       // num components
#define HP  144     // padded hidden (N-dim, 9 tiles of 16)
#define KP  160     // padded K-dim for hidden layers (5 steps of 32)

typedef short bf16x8 __attribute__((ext_vector_type(8)));
typedef float f32x4  __attribute__((ext_vector_type(4)));

__device__ __forceinline__ unsigned short f2b(float f){
  union{float f; unsigned u;} c; c.f = f;
  unsigned r = c.u + 0x7fffu + ((c.u >> 16) & 1u);   // RNE
  return (unsigned short)(r >> 16);
}

// ---------------- prep A: Wf = Wu @ Wm (fp32), bfv = K*(Wu@bm) + bu ----------------
__global__ void prepA(const float* __restrict__ Wm, const float* __restrict__ bm,
                      const float* __restrict__ Wu, const float* __restrict__ bu,
                      float* __restrict__ Wf, float* __restrict__ bfv){
  int idx = blockIdx.x * 256 + threadIdx.x;      // 64 blocks -> 16384 = 128*128
  int i = idx >> 7, j = idx & 127;
  float acc = 0.f;
  for(int d = 0; d < DD; ++d)
    acc += Wu[i*DD + d] * Wm[d*DD + j];
  Wf[idx] = acc;
  if(j == 0){
    float a = 0.f;
    for(int d = 0; d < DD; ++d) a += Wu[i*DD + d] * bm[d];
    bfv[i] = (float)KKC * a + bu[i];
  }
}

// ---------------- prep B: fused + padded bf16 weights into workspace ----------------
// segments: w0s_p[144][128], w0rp[144][128], w1p[144][160], w2p[144][160],
//           w3p[128][160], b0p[144], b1p[144], b2p[144], b3p[128]  (biases fp32)
__global__ void prepB(const float* __restrict__ W0, const float* __restrict__ b0,
                      const float* __restrict__ W1, const float* __restrict__ b1,
                      const float* __restrict__ W2, const float* __restrict__ b2,
                      const float* __restrict__ W3, const float* __restrict__ b3,
                      const float* __restrict__ Wf, const float* __restrict__ bfv,
                      unsigned short* __restrict__ w0s_p, unsigned short* __restrict__ w0rp,
                      unsigned short* __restrict__ w1p,  unsigned short* __restrict__ w2p,
                      unsigned short* __restrict__ w3p,
                      float* __restrict__ b0p, float* __restrict__ b1p,
                      float* __restrict__ b2p, float* __restrict__ b3p){
  int idx = blockIdx.x * 256 + threadIdx.x;
  if(idx < HP*DD){                                  // w0s_p: signal half of W0, padded
    int n = idx >> 7, k = idx & 127;
    w0s_p[idx] = (n < HH) ? f2b(W0[n*(2*DD) + k]) : (unsigned short)0;
    return;
  }
  idx -= HP*DD;
  if(idx < HP*DD){                                  // w0rp = W0r @ Wf, padded
    int n = idx >> 7, k = idx & 127;
    float acc = 0.f;
    if(n < HH)
      for(int i = 0; i < DD; ++i)
        acc += W0[n*(2*DD) + DD + i] * Wf[i*DD + k];
    w0rp[idx] = (n < HH) ? f2b(acc) : (unsigned short)0;
    return;
  }
  idx -= HP*DD;
  if(idx < HP*KP){                                  // w1p padded
    int n = idx / KP, k = idx % KP;
    w1p[idx] = (n < HH && k < HH) ? f2b(W1[n*HH + k]) : (unsigned short)0;
    return;
  }
  idx -= HP*KP;
  if(idx < HP*KP){                                  // w2p padded
    int n = idx / KP, k = idx % KP;
    w2p[idx] = (n < HH && k < HH) ? f2b(W2[n*HH + k]) : (unsigned short)0;
    return;
  }
  idx -= HP*KP;
  if(idx < DD*KP){                                  // w3p padded (N=128 full, K pad)
    int n = idx / KP, k = idx % KP;
    w3p[idx] = (k < HH) ? f2b(W3[n*HH + k]) : (unsigned short)0;
    return;
  }
  idx -= DD*KP;
  if(idx < HP){                                     // b0p = b0 + W0r @ bfv, padded
    float acc = 0.f;
    if(idx < HH){
      acc = b0[idx];
      for(int i = 0; i < DD; ++i) acc += W0[idx*(2*DD) + DD + i] * bfv[i];
    }
    b0p[idx] = acc;
    return;
  }
  idx -= HP;
  if(idx < HP){ b1p[idx] = (idx < HH) ? b1[idx] : 0.f; return; }
  idx -= HP;
  if(idx < HP){ b2p[idx] = (idx < HH) ? b2[idx] : 0.f; return; }
  idx -= HP;
  if(idx < DD){ b3p[idx] = b3[idx]; return; }
}

// ---------------- fused hot kernel ----------------
// 256 threads = 4 waves; each wave owns 16 batch rows. Grid = B/64 = 1024 blocks.
// MFMA 16x16x32 bf16 verified layouts:
//   A frag : lane holds A[m=lane&15][k = (lane>>4)*8 + j], j=0..7
//   B frag : lane holds B[k = (lane>>4)*8 + j][n = lane&15]  -> W[n][k..k+7] row-major
//   C/D    : lane holds D[row = (lane>>4)*4 + r][col = lane&15]
__global__ __launch_bounds__(256) void fused_msgprop(
    const float* __restrict__ signal,
    const float* __restrict__ comps,
    const unsigned short* __restrict__ w0s_p,
    const unsigned short* __restrict__ w0rp,
    const unsigned short* __restrict__ w1p,
    const unsigned short* __restrict__ w2p,
    const unsigned short* __restrict__ w3p,
    const float* __restrict__ b0p, const float* __restrict__ b1p,
    const float* __restrict__ b2p, const float* __restrict__ b3p,
    float* __restrict__ out)
{
  const int tid  = threadIdx.x;
  const int lane = tid & 63;
  const int wave = tid >> 6;
  const int m    = lane & 15;
  const int quad = lane >> 4;
  const int rowBase = blockIdx.x * 64 + wave * 16;

  // per-wave private 16 x KP activation tile; stride 168 elts (336 B = 21*16B) keeps
  // ds_read_b128 column-reads at worst 2-way bank aliasing (free on CDNA4)
  __shared__ unsigned short lds[4][16][168];

  // zero the K-pad columns [144,160) once (never written by compute)
  for(int t = tid; t < 4*16*16; t += 256){
    int wv = t >> 8, r = (t >> 4) & 15, c = t & 15;
    lds[wv][r][144 + c] = 0;
  }
  __syncthreads();

  const int arow = rowBase + m;

  // ---- signal A-fragments (K = 128 -> 4 frags), fp32 load -> bf16 round ----
  bf16x8 sigf[4];
  {
    const float* srow = signal + (size_t)arow * DD;
    #pragma unroll
    for(int ki = 0; ki < 4; ++ki){
      f32x4 lo = *(const f32x4*)(srow + ki*32 + quad*8);
      f32x4 hi = *(const f32x4*)(srow + ki*32 + quad*8 + 4);
      bf16x8 p;
      #pragma unroll
      for(int j = 0; j < 4; ++j){ p[j] = (short)f2b(lo[j]); p[4+j] = (short)f2b(hi[j]); }
      sigf[ki] = p;
    }
  }

  // ---- component-sum A-fragments (fp32 accumulate over K components) ----
  bf16x8 compf[4];
  {
    float a[4][8];
    #pragma unroll
    for(int ki = 0; ki < 4; ++ki)
      #pragma unroll
      for(int j = 0; j < 8; ++j) a[ki][j] = 0.f;
    #pragma unroll
    for(int k = 0; k < KKC; ++k){
      const float* crow = comps + ((size_t)k * BB + arow) * DD;
      #pragma unroll
      for(int ki = 0; ki < 4; ++ki){
        f32x4 lo = *(const f32x4*)(crow + ki*32 + quad*8);
        f32x4 hi = *(const f32x4*)(crow + ki*32 + quad*8 + 4);
        #pragma unroll
        for(int j = 0; j < 4; ++j){ a[ki][j] += lo[j]; a[ki][4+j] += hi[j]; }
      }
    }
    #pragma unroll
    for(int ki = 0; ki < 4; ++ki){
      bf16x8 p;
      #pragma unroll
      for(int j = 0; j < 8; ++j) p[j] = (short)f2b(a[ki][j]);
      compf[ki] = p;
    }
  }

  // ---- layer 0: h0 = relu(sig @ W0s^T + compsum @ W0rp^T + b0p)  [N=144, K=128+128]
  #pragma unroll
  for(int nt = 0; nt < 9; ++nt){
    f32x4 acc = {0.f,0.f,0.f,0.f};
    const unsigned short* wr1 = w0s_p + (size_t)(nt*16 + m)*DD + quad*8;
    const unsigned short* wr2 = w0rp  + (size_t)(nt*16 + m)*DD + quad*8;
    #pragma unroll
    for(int ki = 0; ki < 4; ++ki){
      bf16x8 wf = *(const bf16x8*)(wr1 + ki*32);
      acc = __builtin_amdgcn_mfma_f32_16x16x32_bf16(sigf[ki], wf, acc, 0, 0, 0);
    }
    #pragma unroll
    for(int ki = 0; ki < 4; ++ki){
      bf16x8 wf = *(const bf16x8*)(wr2 + ki*32);
      acc = __builtin_amdgcn_mfma_f32_16x16x32_bf16(compf[ki], wf, acc, 0, 0, 0);
    }
    float bias = b0p[nt*16 + m];
    #pragma unroll
    for(int r = 0; r < 4; ++r){
      float v = acc[r] + bias;
      v = v > 0.f ? v : 0.f;
      lds[wave][quad*4 + r][nt*16 + m] = f2b(v);
    }
  }
  __syncthreads();

  bf16x8 hf[5];

  // ---- layer 1 ----
  #pragma unroll
  for(int ki = 0; ki < 5; ++ki)
    hf[ki] = *(const bf16x8*)&lds[wave][m][ki*32 + quad*8];
  __syncthreads();
  #pragma unroll
  for(int nt = 0; nt < 9; ++nt){
    f32x4 acc = {0.f,0.f,0.f,0.f};
    const unsigned short* wr = w1p + (size_t)(nt*16 + m)*KP + quad*8;
    #pragma unroll
    for(int ki = 0; ki < 5; ++ki){
      bf16x8 wf = *(const bf16x8*)(wr + ki*32);
      acc = __builtin_amdgcn_mfma_f32_16x16x32_bf16(hf[ki], wf, acc, 0, 0, 0);
    }
    float bias = b1p[nt*16 + m];
    #pragma unroll
    for(int r = 0; r < 4; ++r){
      float v = acc[r] + bias;
      v = v > 0.f ? v : 0.f;
      lds[wave][quad*4 + r][nt*16 + m] = f2b(v);
    }
  }
  __syncthreads();

  // ---- layer 2 ----
  #pragma unroll
  for(int ki = 0; ki < 5; ++ki)
    hf[ki] = *(const bf16x8*)&lds[wave][m][ki*32 + quad*8];
  __syncthreads();
  #pragma unroll
  for(int nt = 0; nt < 9; ++nt){
    f32x4 acc = {0.f,0.f,0.f,0.f};
    const unsigned short* wr = w2p + (size_t)(nt*16 + m)*KP + quad*8;
    #pragma unroll
    for(int ki = 0; ki < 5; ++ki){
      bf16x8 wf = *(const bf16x8*)(wr + ki*32);
      acc = __builtin_amdgcn_mfma_f32_16x16x32_bf16(hf[ki], wf, acc, 0, 0, 0);
    }
    float bias = b2p[nt*16 + m];
    #pragma unroll
    for(int r = 0; r < 4; ++r){
      float v = acc[r] + bias;
      v = v > 0.f ? v : 0.f;
      lds[wave][quad*4 + r][nt*16 + m] = f2b(v);
    }
  }
  __syncthreads();

  // ---- layer 3: out = h2 @ W3^T + b3  [N=128, K=160], fp32 output ----
  #pragma unroll
  for(int ki = 0; ki < 5; ++ki)
    hf[ki] = *(const bf16x8*)&lds[wave][m][ki*32 + quad*8];
  #pragma unroll
  for(int nt = 0; nt < 8; ++nt){
    f32x4 acc = {0.f,0.f,0.f,0.f};
    const unsigned short* wr = w3p + (size_t)(nt*16 + m)*KP + quad*8;
    #pragma unroll
    for(int ki = 0; ki < 5; ++ki){
      bf16x8 wf = *(const bf16x8*)(wr + ki*32);
      acc = __builtin_amdgcn_mfma_f32_16x16x32_bf16(hf[ki], wf, acc, 0, 0, 0);
    }
    float bias = b3p[nt*16 + m];
    #pragma unroll
    for(int r = 0; r < 4; ++r){
      int grow = rowBase + quad*4 + r;
      out[(size_t)grow*DD + nt*16 + m] = acc[r] + bias;
    }
  }
}

extern "C" void kernel_launch(void* const* d_in, const int* in_sizes, int n_in,
                              void* d_out, int out_size, void* d_ws, size_t ws_size,
                              hipStream_t stream){
  const float* signal = (const float*)d_in[0];
  const float* comps  = (const float*)d_in[1];
  const float* Wm = (const float*)d_in[2];
  const float* bm = (const float*)d_in[3];
  const float* Wu = (const float*)d_in[4];
  const float* bu = (const float*)d_in[5];
  const float* W0 = (const float*)d_in[6];
  const float* b0 = (const float*)d_in[7];
  const float* W1 = (const float*)d_in[8];
  const float* b1 = (const float*)d_in[9];
  const float* W2 = (const float*)d_in[10];
  const float* b2 = (const float*)d_in[11];
  const float* W3 = (const float*)d_in[12];
  const float* b3 = (const float*)d_in[13];

  char* ws = (char*)d_ws;
  float*          Wf    = (float*)(ws + 0);        // 128*128*4 = 65536
  float*          bfv   = (float*)(ws + 65536);    // 128*4 -> 512 (pad to 66048)
  unsigned short* w0s_p = (unsigned short*)(ws + 66048);   // 144*128*2 = 36864
  unsigned short* w0rp  = (unsigned short*)(ws + 102912);  // 36864
  unsigned short* w1p   = (unsigned short*)(ws + 139776);  // 144*160*2 = 46080
  unsigned short* w2p   = (unsigned short*)(ws + 185856);  // 46080
  unsigned short* w3p   = (unsigned short*)(ws + 231936);  // 128*160*2 = 40960
  float*          b0p   = (float*)(ws + 272896);   // 576
  float*          b1p   = (float*)(ws + 273472);
  float*          b2p   = (float*)(ws + 274048);
  float*          b3p   = (float*)(ws + 274624);

  hipLaunchKernelGGL(prepA, dim3(64), dim3(256), 0, stream, Wm, bm, Wu, bu, Wf, bfv);

  // total prepB items: 18432+18432+23040+23040+20480+144+144+144+128 = 103984
  hipLaunchKernelGGL(prepB, dim3(407), dim3(256), 0, stream,
                     W0, b0, W1, b1, W2, b2, W3, b3, Wf, bfv,
                     w0s_p, w0rp, w1p, w2p, w3p, b0p, b1p, b2p, b3p);

  hipLaunchKernelGGL(fused_msgprop, dim3(BB/64), dim3(256), 0, stream,
                     signal, comps, w0s_p, w0rp, w1p, w2p, w3p,
                     b0p, b1p, b2p, b3p, (float*)d_out);
}